// Round 6
// baseline (238.926 us; speedup 1.0000x reference)
//
#include <hip/hip_runtime.h>
#include <math.h>

#define KB 16

// Native clang vector type — required for __builtin_nontemporal_load/store.
typedef float vf4 __attribute__((ext_vector_type(4)));

// ws layout (floats): [0..31] interleaved (gamma,beta) pairs, [32..47] zval,
// [48] alpha, [49] 1/alpha.
#define WS_FLOATS 50

// ---------------------------------------------------------------------------
// Setup kernel: runs ONCE (1 block), computes the 16-entry tables and writes
// them to d_ws. Identical fp32 op order to rounds 1-5 (absmax was exactly 0.0).
// ---------------------------------------------------------------------------
__global__ __launch_bounds__(64) void lcq_setup_kernel(
    const float* __restrict__ thr,
    const float* __restrict__ theta,
    float* __restrict__ ws)
{
    if (threadIdx.x != 0) return;

    float th[KB];
    float mx = theta[0];
    th[0] = mx;
    #pragma unroll
    for (int i = 1; i < KB; ++i) { th[i] = theta[i]; mx = fmaxf(mx, th[i]); }
    float ex[KB];
    float sum = 0.0f;
    #pragma unroll
    for (int i = 0; i < KB; ++i) { ex[i] = expf(__fsub_rn(th[i], mx)); sum = __fadd_rn(sum, ex[i]); }
    float sm[KB];
    #pragma unroll
    for (int i = 0; i < KB; ++i) sm[i] = __fdiv_rn(ex[i], sum);

    float beta[KB], gamma[KB];
    beta[0] = 0.0f;
    float c = sm[0];
    #pragma unroll
    for (int i = 1; i < KB; ++i) { beta[i] = c; c = __fadd_rn(c, sm[i]); }
    #pragma unroll
    for (int i = 0; i < KB; ++i) gamma[i] = __fmul_rn(sm[i], 16.0f);

    #pragma unroll
    for (int i = 0; i < KB; ++i) {
        ws[2 * i]     = gamma[i];
        ws[2 * i + 1] = beta[i];
    }
    // zval[m] = expand(m/15): second searchsorted + inverse affine
    for (int m = 0; m < KB; ++m) {
        float yq = __fdiv_rn((float)m, 15.0f);
        int iq = 0;
        #pragma unroll
        for (int i = 1; i < KB; ++i) iq += (beta[i] <= yq) ? 1 : 0;
        ws[32 + m] = __fadd_rn(__fdiv_rn(__fsub_rn(yq, beta[iq]), gamma[iq]),
                               (float)iq * 0.0625f);
    }
    float alpha = thr[0];
    ws[48] = alpha;
    ws[49] = __fdiv_rn(1.0f, alpha);   // exact for pow2 alpha (bench: 1.0)
}

// ---------------------------------------------------------------------------
// Per-element core. Faithful fp32 op order vs reference (__f*_rn blocks FMA
// contraction; rintf == round-half-even == jnp.round). Rounds 1/3/4/5: absmax 0.0.
// ---------------------------------------------------------------------------
__device__ __forceinline__ float lcq_core(float xv, float alpha, float rcp_alpha,
                                          const float2* __restrict__ s_gb,
                                          const float* __restrict__ s_zval)
{
    float a   = fabsf(xv);
    float xt  = __fmul_rn(a, rcp_alpha);            // x_tmp = |x|/alpha
    float t16 = __fmul_rn(xt, 16.0f);               // exact pow2 scale
    float jf  = fminf(t16, 15.0f);
    int   j   = (int)jf;                            // searchsorted(dst,·,right)-1
    float2 gb = s_gb[j];                            // ds_read_b64, broadcast-friendly
    float dj  = __fmul_rn(floorf(jf), 0.0625f);     // dst[j] = j/16, exact
    float y   = __fadd_rn(__fmul_rn(gb.x, __fsub_rn(xt, dj)), gb.y);
    float t   = rintf(__fmul_rn(y, 15.0f));         // m = round(y*s), half-even; t>=0
    int   m   = (int)fminf(t, 15.0f);
    float v   = (a < alpha) ? s_zval[m] : 1.0f;     // flag_middle select
    float r   = __fmul_rn(alpha, v);
    return copysignf(r, xv);                        // x==0 -> 0 exactly (zval[0]==0)
}

// One-shot blocks: block b owns float4 indices [b*1024,(b+1)*1024) — contiguous
// 64KB. Table SETUP IS HOISTED to lcq_setup_kernel; each block only does a
// 50-lane global->LDS copy (~200cyc L2 hit) instead of ~700 serial VALU inst.
__global__ __launch_bounds__(256) void lcq_kernel(
    const float* __restrict__ x,
    const float* __restrict__ ws,
    float* __restrict__ out,
    long long n)
{
    __shared__ __align__(16) float s_tab[WS_FLOATS];

    if (threadIdx.x < WS_FLOATS) s_tab[threadIdx.x] = ws[threadIdx.x];
    __syncthreads();

    const float2* s_gb   = (const float2*)s_tab;   // 16 (gamma,beta) pairs
    const float*  s_zval = s_tab + 32;             // 16 zval entries
    const float alpha = s_tab[48];
    const float rcpa  = s_tab[49];

    const long long n4ll = n >> 2;
    const vf4* __restrict__ x4 = (const vf4*)x;
    vf4* __restrict__ o4 = (vf4*)out;

    const unsigned base = blockIdx.x * 1024u + threadIdx.x;  // float4 index

    if ((long long)(blockIdx.x + 1) * 1024ll <= n4ll) {
        // Full-block fast path (only path at bench shape: 8192 exact blocks).
        vf4 v0 = __builtin_nontemporal_load(&x4[base]);
        vf4 v1 = __builtin_nontemporal_load(&x4[base + 256u]);
        vf4 v2 = __builtin_nontemporal_load(&x4[base + 512u]);
        vf4 v3 = __builtin_nontemporal_load(&x4[base + 768u]);
        vf4 r0, r1, r2, r3;
        r0.x = lcq_core(v0.x, alpha, rcpa, s_gb, s_zval);
        r0.y = lcq_core(v0.y, alpha, rcpa, s_gb, s_zval);
        r0.z = lcq_core(v0.z, alpha, rcpa, s_gb, s_zval);
        r0.w = lcq_core(v0.w, alpha, rcpa, s_gb, s_zval);
        r1.x = lcq_core(v1.x, alpha, rcpa, s_gb, s_zval);
        r1.y = lcq_core(v1.y, alpha, rcpa, s_gb, s_zval);
        r1.z = lcq_core(v1.z, alpha, rcpa, s_gb, s_zval);
        r1.w = lcq_core(v1.w, alpha, rcpa, s_gb, s_zval);
        r2.x = lcq_core(v2.x, alpha, rcpa, s_gb, s_zval);
        r2.y = lcq_core(v2.y, alpha, rcpa, s_gb, s_zval);
        r2.z = lcq_core(v2.z, alpha, rcpa, s_gb, s_zval);
        r2.w = lcq_core(v2.w, alpha, rcpa, s_gb, s_zval);
        r3.x = lcq_core(v3.x, alpha, rcpa, s_gb, s_zval);
        r3.y = lcq_core(v3.y, alpha, rcpa, s_gb, s_zval);
        r3.z = lcq_core(v3.z, alpha, rcpa, s_gb, s_zval);
        r3.w = lcq_core(v3.w, alpha, rcpa, s_gb, s_zval);
        __builtin_nontemporal_store(r0, &o4[base]);
        __builtin_nontemporal_store(r1, &o4[base + 256u]);
        __builtin_nontemporal_store(r2, &o4[base + 512u]);
        __builtin_nontemporal_store(r3, &o4[base + 768u]);
    } else {
        // Partial last block (not hit at bench shape; kept for generality).
        #pragma unroll
        for (int k = 0; k < 4; ++k) {
            long long i = (long long)base + k * 256;
            if (i < n4ll) {
                vf4 v = x4[i];
                vf4 r;
                r.x = lcq_core(v.x, alpha, rcpa, s_gb, s_zval);
                r.y = lcq_core(v.y, alpha, rcpa, s_gb, s_zval);
                r.z = lcq_core(v.z, alpha, rcpa, s_gb, s_zval);
                r.w = lcq_core(v.w, alpha, rcpa, s_gb, s_zval);
                o4[i] = r;
            }
        }
        if (blockIdx.x == gridDim.x - 1) {
            for (long long k = (n4ll << 2) + threadIdx.x; k < n; k += 256) {
                out[k] = lcq_core(x[k], alpha, rcpa, s_gb, s_zval);
            }
        }
    }
}

extern "C" void kernel_launch(void* const* d_in, const int* in_sizes, int n_in,
                              void* d_out, int out_size, void* d_ws, size_t ws_size,
                              hipStream_t stream) {
    const float* x     = (const float*)d_in[0];   // (4,4096,2048) fp32
    const float* thr   = (const float*)d_in[1];   // (1,) alpha
    const float* theta = (const float*)d_in[2];   // (16,)
    float* out = (float*)d_out;
    float* ws  = (float*)d_ws;                    // 50 floats of table

    long long n = (long long)in_sizes[0];
    long long n4 = n >> 2;
    long long grid = (n4 + 1023) / 1024;          // bench: 8192 one-shot blocks
    if (grid < 1) grid = 1;

    // 1) build tables once (ws is re-poisoned before every call — always rerun)
    hipLaunchKernelGGL(lcq_setup_kernel, dim3(1), dim3(64), 0, stream,
                       thr, theta, ws);
    // 2) stream (stream-ordered: setup completes, L2 flushed at dispatch end)
    hipLaunchKernelGGL(lcq_kernel, dim3((unsigned)grid), dim3(256), 0, stream,
                       x, ws, out, n);
}